// Round 4
// baseline (170.086 us; speedup 1.0000x reference)
//
#include <hip/hip_runtime.h>
#include <cstdint>

// ---------------------------------------------------------------------------
// QuantumCoherentLayer collapsed:
//   out[b,h2] = sum_p wHI[p]*coh[b,p,h2] + (x @ Win @ WeffLO)[b,h2]
//   w[j] = (alpha/64)*colsum_j(softmax_rows(cos(phase*J_sym)));
//   wLO = w*(1-alpha) folded into Weff; wHI = w*alpha.
// All GEMM intermediates are stored in MFMA fragment order so the GEMMs are
// LDS-free / barrier-free: frag slot = ((rt*32 + kt)*64 + lane)*8 shorts,
// lane=(r%16)+16*((k%32)/8) holding elements k%8..+7 (m89-verified mapping,
// identical for A and B operands).
// ---------------------------------------------------------------------------

typedef __attribute__((ext_vector_type(8))) __bf16 bf16x8;
typedef __attribute__((ext_vector_type(4))) float f32x4;
typedef unsigned short u16;

__device__ __forceinline__ u16 f32_to_bf16_rne(float f) {
  unsigned int u = __float_as_uint(f);
  u += 0x7fffu + ((u >> 16) & 1u);
  return (u16)(u >> 16);
}

// Per-wave scalars; every lane ends with w for j=(lane&7) plus alpha.
__device__ __forceinline__ void wave_scalars(const float* __restrict__ J,
                                             const float* __restrict__ t,
                                             float* w_out, float* alpha_out) {
  const int lane = threadIdx.x & 63;
  float tv = t[0];
  float alpha = fminf(fmaxf(expf(-tv / 51.0f), 0.0f), 1.0f);
  float phase = 2.0f * 3.14159265358979323846f * 20.0f * tv / 1000.0f;
  int i = lane >> 3, j = lane & 7;
  float jsym = 0.5f * (J[i * 8 + j] + J[j * 8 + i]);
  float e = expf(cosf(phase * jsym));
  float rs = e;
  rs += __shfl_xor(rs, 1);
  rs += __shfl_xor(rs, 2);
  rs += __shfl_xor(rs, 4);
  float p = e / rs;
  float cs = p;
  cs += __shfl_xor(cs, 8);
  cs += __shfl_xor(cs, 16);
  cs += __shfl_xor(cs, 32);
  *w_out = alpha * (1.0f / 64.0f) * cs;
  *alpha_out = alpha;
}

// ---------------------------------------------------------------------------
// k_prep, 960 blocks x 256:
//  [0,256)   : wefft frag build (64x64 tile of sum_j wLO[j]*Wp[j][h1][h2],
//              transposed to rows=h2, k=h1, written in frag order)
//  [256,768) : out[b][h2] = sum_p wHI[p]*coh[b][p][h2] (fp32 partial, 4 f4/thr)
//  [768,960) : x (128 blks) / Win (64 blks) fp32 -> bf16 frag via LDS tile
// ---------------------------------------------------------------------------
__global__ __launch_bounds__(256) void k_prep(
    const float* __restrict__ x, const float* __restrict__ win,
    const float* __restrict__ wp, const float* __restrict__ J,
    const float* __restrict__ t, const float* __restrict__ coh,
    u16* __restrict__ xfrag, u16* __restrict__ winfrag,
    u16* __restrict__ wefrag, float* __restrict__ out) {
  __shared__ __align__(16) char smem[33024];
  const int blk = blockIdx.x;
  const int tid = threadIdx.x;
  const int lane = tid & 63;

  if (blk < 256) {
    // ---- wefft frag build ----
    float* lt = (float*)smem;  // [64][69]  lt[h1l][h2l]
    float wv, alpha;
    wave_scalars(J, t, &wv, &alpha);
    float wLO[8];
#pragma unroll
    for (int p = 0; p < 8; p++)
      wLO[p] = __shfl(wv, (lane & 56) | p) * (1.0f - alpha);
    const int a0 = (blk & 15) * 64;   // h1 base
    const int b0 = (blk >> 4) * 64;   // h2 base
    const int rb = tid >> 4, c = tid & 15;
    f32x4 acc[4];
#pragma unroll
    for (int s = 0; s < 4; s++) acc[s] = (f32x4){0.f, 0.f, 0.f, 0.f};
#pragma unroll
    for (int j = 0; j < 8; j++) {
      const float* base = wp + (size_t)j * 1048576 + b0 + c * 4;
      float wj = wLO[j];
#pragma unroll
      for (int s = 0; s < 4; s++)
        acc[s] += wj * *(const f32x4*)(base + (size_t)(a0 + rb + 16 * s) * 1024);
    }
#pragma unroll
    for (int s = 0; s < 4; s++)
#pragma unroll
      for (int e = 0; e < 4; e++) lt[(rb + 16 * s) * 69 + c * 4 + e] = acc[s][e];
    __syncthreads();
#pragma unroll
    for (int s2 = 0; s2 < 2; s2++) {
      int idx = s2 * 256 + tid;
      int lf = idx & 63, ktl = (idx >> 6) & 1, rtl = idx >> 7;
      int h2l = rtl * 16 + (lf & 15);
      int h1b = ktl * 32 + ((lf >> 4) << 3);
      __align__(16) u16 o[8];
#pragma unroll
      for (int i = 0; i < 8; i++)
        o[i] = f32_to_bf16_rne(lt[(h1b + i) * 69 + h2l]);
      int rt = (b0 >> 4) + rtl, kt = (a0 >> 5) + ktl;
      *(uint4*)(wefrag + ((size_t)(rt * 32 + kt) * 64 + lf) * 8) = *(const uint4*)o;
    }
  } else if (blk < 768) {
    // ---- coh partial -> out ----
    float wv, alpha;
    wave_scalars(J, t, &wv, &alpha);
    float wHI[8];
#pragma unroll
    for (int p = 0; p < 8; p++) wHI[p] = __shfl(wv, (lane & 56) | p) * alpha;
    const f32x4* c4 = (const f32x4*)coh;
    f32x4* o4 = (f32x4*)out;
    const int base = (blk - 256) * 256 + tid;
#pragma unroll
    for (int u = 0; u < 4; u++) {
      int idx = base + u * 131072;
      int b = idx >> 8, hq = idx & 255;
      const f32x4* cb = c4 + (size_t)b * 2048 + hq;
      f32x4 acc = {0.f, 0.f, 0.f, 0.f};
#pragma unroll
      for (int p = 0; p < 8; p++) acc += wHI[p] * cb[p * 256];
      o4[idx] = acc;
    }
  } else {
    // ---- fp32 [16 rows x 1024] -> bf16 frag, via LDS tile ----
    const int cid = blk - 768;
    const float* src;
    u16* dst;
    if (cid < 128) {
      src = x + (size_t)cid * 16384;
      dst = xfrag + (size_t)cid * 16384;       // rt = cid
    } else {
      src = win + (size_t)(cid - 128) * 16384;
      dst = winfrag + (size_t)(cid - 128) * 16384;
    }
    u16* ld = (u16*)smem;  // [16][1032] padded
#pragma unroll
    for (int i = 0; i < 16; i++) {
      int idx = i * 256 + tid;
      int row = idx >> 8, c4i = idx & 255;
      f32x4 v = *(const f32x4*)(src + row * 1024 + c4i * 4);
      ushort4 o;
      o.x = f32_to_bf16_rne(v.x);
      o.y = f32_to_bf16_rne(v.y);
      o.z = f32_to_bf16_rne(v.z);
      o.w = f32_to_bf16_rne(v.w);
      *(ushort4*)(ld + row * 1032 + c4i * 4) = o;
    }
    __syncthreads();
#pragma unroll
    for (int s = 0; s < 8; s++) {
      int idx = s * 256 + tid;
      int lf = idx & 63, kt = idx >> 6;
      int row = lf & 15, colb = kt * 32 + ((lf >> 4) << 3);
      *(uint4*)(dst + (kt * 64 + lf) * 8) = *(const uint4*)(ld + row * 1032 + colb);
    }
  }
}

// ---------------------------------------------------------------------------
// Fragment-direct GEMM, K=1024 (32 k-tiles), no LDS staging, no barriers in
// the K-loop. Block = 4 waves (2x2), wave tile = (FM*16) x 32, BN=64.
// RMW=1: out fp32 += acc (coh partial already there).
// RMW=0: write bf16 in frag order via LDS transpose (for the next GEMM).
// ---------------------------------------------------------------------------
template <int FM, int RMW>
__global__ __launch_bounds__(256) void k_fgemm(
    const u16* __restrict__ Af, const u16* __restrict__ Bf,
    float* __restrict__ outf, u16* __restrict__ ofrag) {
  const int tid = threadIdx.x;
  const int wave = tid >> 6, lane = tid & 63;
  const int quad = lane >> 4, t16 = lane & 15;
  const int m0 = blockIdx.x * (FM * 32);
  const int n0 = blockIdx.y * 64;
  const int wm = (wave >> 1) * (FM * 16);
  const int wn = (wave & 1) * 32;
  const u16* ap = Af + (size_t)(((m0 + wm) >> 4) * 32) * 512 + lane * 8;
  const u16* bp = Bf + (size_t)(((n0 + wn) >> 4) * 32) * 512 + lane * 8;

  f32x4 acc[FM][2];
#pragma unroll
  for (int mi = 0; mi < FM; mi++)
#pragma unroll
    for (int ni = 0; ni < 2; ni++) acc[mi][ni] = (f32x4){0.f, 0.f, 0.f, 0.f};

#pragma unroll 4
  for (int kt = 0; kt < 32; kt++) {
    bf16x8 a[FM], b[2];
#pragma unroll
    for (int mi = 0; mi < FM; mi++)
      a[mi] = *(const bf16x8*)(ap + (mi * 32 + kt) * 512);
#pragma unroll
    for (int ni = 0; ni < 2; ni++)
      b[ni] = *(const bf16x8*)(bp + (ni * 32 + kt) * 512);
#pragma unroll
    for (int mi = 0; mi < FM; mi++)
#pragma unroll
      for (int ni = 0; ni < 2; ni++)
        acc[mi][ni] = __builtin_amdgcn_mfma_f32_16x16x32_bf16(a[mi], b[ni],
                                                              acc[mi][ni], 0, 0, 0);
  }

  if constexpr (RMW) {
    // C layout: row = quad*4 + r, col = t16
#pragma unroll
    for (int mi = 0; mi < FM; mi++)
#pragma unroll
      for (int r = 0; r < 4; r++) {
        size_t mrow = (size_t)(m0 + wm + mi * 16 + quad * 4 + r) * 1024;
#pragma unroll
        for (int ni = 0; ni < 2; ni++) {
          size_t off = mrow + n0 + wn + ni * 16 + t16;
          outf[off] += acc[mi][ni][r];
        }
      }
  } else {
    __shared__ u16 ct[64 * 72];
#pragma unroll
    for (int mi = 0; mi < FM; mi++)
#pragma unroll
      for (int r = 0; r < 4; r++)
#pragma unroll
        for (int ni = 0; ni < 2; ni++)
          ct[(wm + mi * 16 + quad * 4 + r) * 72 + wn + ni * 16 + t16] =
              f32_to_bf16_rne(acc[mi][ni][r]);
    __syncthreads();
#pragma unroll
    for (int s2 = 0; s2 < 2; s2++) {
      int idx = s2 * 256 + tid;
      int lf = idx & 63, ktl = (idx >> 6) & 1, rtl = idx >> 7;
      int rowl = rtl * 16 + (lf & 15);
      int colb = ktl * 32 + ((lf >> 4) << 3);
      int rt = (m0 >> 4) + rtl, kt = (n0 >> 5) + ktl;
      *(uint4*)(ofrag + ((size_t)(rt * 32 + kt) * 64 + lf) * 8) =
          *(const uint4*)(ct + rowl * 72 + colb);
    }
  }
}

// ---------------------------------------------------------------------------
extern "C" void kernel_launch(void* const* d_in, const int* in_sizes, int n_in,
                              void* d_out, int out_size, void* d_ws, size_t ws_size,
                              hipStream_t stream) {
  const float* x   = (const float*)d_in[0];  // [2048,1024]
  const float* win = (const float*)d_in[1];  // [1024,1024]
  const float* wp  = (const float*)d_in[2];  // [8,1024,1024]
  const float* J   = (const float*)d_in[3];  // [8,8]
  const float* coh = (const float*)d_in[4];  // [2048,8,1024]
  const float* t   = (const float*)d_in[5];  // [1]
  float* out = (float*)d_out;                // [2048,1024] fp32

  char* ws = (char*)d_ws;
  u16* xfrag   = (u16*)ws;                         // 4 MB, rt=b/16
  u16* winfrag = (u16*)(ws + 4u * 1024 * 1024);    // 2 MB, rt=d/16, kt=h1/32
  u16* wefrag  = (u16*)(ws + 6u * 1024 * 1024);    // 2 MB, rt=h2/16, kt=h1/32
  u16* wctfrag = (u16*)(ws + 8u * 1024 * 1024);    // 2 MB, rt=h2/16, kt=d/32

  k_prep<<<960, 256, 0, stream>>>(x, win, wp, J, t, coh, xfrag, winfrag, wefrag,
                                  out);
  // wct[h2][d] = sum_h1 wefft[h2][h1] * win[d][h1]
  k_fgemm<2, 0><<<dim3(16, 16), 256, 0, stream>>>(wefrag, winfrag, nullptr,
                                                  wctfrag);
  // out[b][h2] += sum_d x[b][d] * wct[h2][d]
  k_fgemm<4, 1><<<dim3(16, 16), 256, 0, stream>>>(xfrag, wctfrag, out, nullptr);
}

// Round 5
// 166.605 us; speedup vs baseline: 1.0209x; 1.0209x over previous
//
#include <hip/hip_runtime.h>
#include <cstdint>

// ---------------------------------------------------------------------------
// QuantumCoherentLayer collapsed:
//   out[b,h2] = sum_p wHI[p]*coh[b,p,h2] + (x @ Win @ WeffLO)[b,h2]
//   w[j] = (alpha/64)*colsum_j(softmax_rows(cos(phase*J_sym)))
//   wLO = w*(1-alpha) folded into Weff; wHI = w*alpha.
// GEMM intermediates live in MFMA fragment order (slot = ((rt*32+kt)*64+lane)*8
// shorts; lane = (row%16) + 16*((k%32)/8) holds k%8..+7) so GEMMs are LDS-free
// and barrier-free in the K-loop.
// k_prep : wefft frag build + x/Win bf16-frag converts
// k_gemm0: wctfrag = wefrag x winfrag  (epilogue LDS-transposes C to B-frag)
// k_main : waves 0-3 fragment GEMM (x @ wct), waves 4-7 stream coh -> LDS;
//          one barrier, merged fp32 store. No out RMW.
// ---------------------------------------------------------------------------

typedef __attribute__((ext_vector_type(8))) __bf16 bf16x8;
typedef __attribute__((ext_vector_type(4))) float f32x4;
typedef unsigned short u16;

__device__ __forceinline__ u16 f32_to_bf16_rne(float f) {
  unsigned int u = __float_as_uint(f);
  u += 0x7fffu + ((u >> 16) & 1u);
  return (u16)(u >> 16);
}

// Per-wave scalars; lane ends with w for j=(lane&7), plus alpha.
__device__ __forceinline__ void wave_scalars(const float* __restrict__ J,
                                             const float* __restrict__ t,
                                             float* w_out, float* alpha_out) {
  const int lane = threadIdx.x & 63;
  float tv = t[0];
  float alpha = fminf(fmaxf(expf(-tv / 51.0f), 0.0f), 1.0f);
  float phase = 2.0f * 3.14159265358979323846f * 20.0f * tv / 1000.0f;
  int i = lane >> 3, j = lane & 7;
  float jsym = 0.5f * (J[i * 8 + j] + J[j * 8 + i]);
  float e = expf(cosf(phase * jsym));
  float rs = e;
  rs += __shfl_xor(rs, 1);
  rs += __shfl_xor(rs, 2);
  rs += __shfl_xor(rs, 4);
  float p = e / rs;
  float cs = p;
  cs += __shfl_xor(cs, 8);
  cs += __shfl_xor(cs, 16);
  cs += __shfl_xor(cs, 32);
  *w_out = alpha * (1.0f / 64.0f) * cs;
  *alpha_out = alpha;
}

// ---------------------------------------------------------------------------
// k_prep, 448 blocks x 256:
//  [0,256)   : wefft frag build (64x64 tile of sum_j wLO[j]*Wp[j][h1][h2],
//              rows=h2, k=h1, LDS transpose, frag-order write)
//  [256,384) : x fp32 -> bf16 frag (16 rows per block)
//  [384,448) : Win fp32 -> bf16 frag
// ---------------------------------------------------------------------------
__global__ __launch_bounds__(256) void k_prep(
    const float* __restrict__ x, const float* __restrict__ win,
    const float* __restrict__ wp, const float* __restrict__ J,
    const float* __restrict__ t, u16* __restrict__ xfrag,
    u16* __restrict__ winfrag, u16* __restrict__ wefrag) {
  __shared__ __align__(16) char smem[33024];
  const int blk = blockIdx.x;
  const int tid = threadIdx.x;
  const int lane = tid & 63;

  if (blk < 256) {
    float* lt = (float*)smem;  // [64][69]  lt[h1l][h2l]
    float wv, alpha;
    wave_scalars(J, t, &wv, &alpha);
    float wLO[8];
#pragma unroll
    for (int p = 0; p < 8; p++)
      wLO[p] = __shfl(wv, (lane & 56) | p) * (1.0f - alpha);
    const int a0 = (blk & 15) * 64;   // h1 base
    const int b0 = (blk >> 4) * 64;   // h2 base
    const int rb = tid >> 4, c = tid & 15;
    f32x4 acc[4];
#pragma unroll
    for (int s = 0; s < 4; s++) acc[s] = (f32x4){0.f, 0.f, 0.f, 0.f};
#pragma unroll
    for (int j = 0; j < 8; j++) {
      const float* base = wp + (size_t)j * 1048576 + b0 + c * 4;
      float wj = wLO[j];
#pragma unroll
      for (int s = 0; s < 4; s++)
        acc[s] += wj * *(const f32x4*)(base + (size_t)(a0 + rb + 16 * s) * 1024);
    }
#pragma unroll
    for (int s = 0; s < 4; s++)
#pragma unroll
      for (int e = 0; e < 4; e++) lt[(rb + 16 * s) * 69 + c * 4 + e] = acc[s][e];
    __syncthreads();
#pragma unroll
    for (int s2 = 0; s2 < 2; s2++) {
      int idx = s2 * 256 + tid;
      int lf = idx & 63, ktl = (idx >> 6) & 1, rtl = idx >> 7;
      int h2l = rtl * 16 + (lf & 15);
      int h1b = ktl * 32 + ((lf >> 4) << 3);
      __align__(16) u16 o[8];
#pragma unroll
      for (int i = 0; i < 8; i++)
        o[i] = f32_to_bf16_rne(lt[(h1b + i) * 69 + h2l]);
      int rt = (b0 >> 4) + rtl, kt = (a0 >> 5) + ktl;
      *(uint4*)(wefrag + ((size_t)(rt * 32 + kt) * 64 + lf) * 8) = *(const uint4*)o;
    }
  } else {
    const int cid = blk - 256;  // [0,128) x ; [128,192) win
    const float* src;
    u16* dst;
    if (cid < 128) {
      src = x + (size_t)cid * 16384;
      dst = xfrag + (size_t)cid * 16384;
    } else {
      src = win + (size_t)(cid - 128) * 16384;
      dst = winfrag + (size_t)(cid - 128) * 16384;
    }
    u16* ld = (u16*)smem;  // [16][1032]
#pragma unroll
    for (int i = 0; i < 16; i++) {
      int idx = i * 256 + tid;
      int row = idx >> 8, c4i = idx & 255;
      f32x4 v = *(const f32x4*)(src + row * 1024 + c4i * 4);
      ushort4 o;
      o.x = f32_to_bf16_rne(v.x);
      o.y = f32_to_bf16_rne(v.y);
      o.z = f32_to_bf16_rne(v.z);
      o.w = f32_to_bf16_rne(v.w);
      *(ushort4*)(ld + row * 1032 + c4i * 4) = o;
    }
    __syncthreads();
#pragma unroll
    for (int s = 0; s < 8; s++) {
      int idx = s * 256 + tid;
      int lf = idx & 63, kt = idx >> 6;
      int row = lf & 15, colb = kt * 32 + ((lf >> 4) << 3);
      *(uint4*)(dst + (kt * 64 + lf) * 8) = *(const uint4*)(ld + row * 1032 + colb);
    }
  }
}

// ---------------------------------------------------------------------------
// k_gemm0: wct frag = wefrag(A, rows h2) x winfrag(B, rows d), K=1024.
// Block: 4 waves stacked in m (wave*16), m-tile 64, n-tile 32. Grid (16,32)
// = 512 blocks. Epilogue LDS-transposes C into B-frag order for k_main.
// ---------------------------------------------------------------------------
__global__ __launch_bounds__(256, 4) void k_gemm0(const u16* __restrict__ Af,
                                                  const u16* __restrict__ Bf,
                                                  u16* __restrict__ ofrag) {
  __shared__ u16 ct[64 * 36];
  const int tid = threadIdx.x;
  const int wave = tid >> 6, lane = tid & 63;
  const int quad = lane >> 4, t16 = lane & 15;
  const int m0 = blockIdx.x * 64;   // h2
  const int n0 = blockIdx.y * 32;   // d
  const u16* ap = Af + ((size_t)((m0 + wave * 16) >> 4) * 32) * 512 + lane * 8;
  const u16* bp = Bf + ((size_t)(n0 >> 4) * 32) * 512 + lane * 8;

  f32x4 acc[2] = {{0.f, 0.f, 0.f, 0.f}, {0.f, 0.f, 0.f, 0.f}};
#pragma unroll 4
  for (int kt = 0; kt < 32; kt++) {
    bf16x8 a = *(const bf16x8*)(ap + kt * 512);
    bf16x8 b0 = *(const bf16x8*)(bp + kt * 512);
    bf16x8 b1 = *(const bf16x8*)(bp + (32 + kt) * 512);
    acc[0] = __builtin_amdgcn_mfma_f32_16x16x32_bf16(a, b0, acc[0], 0, 0, 0);
    acc[1] = __builtin_amdgcn_mfma_f32_16x16x32_bf16(a, b1, acc[1], 0, 0, 0);
  }
  // C layout: row = quad*4+r, col = t16
#pragma unroll
  for (int r = 0; r < 4; r++)
#pragma unroll
    for (int ni = 0; ni < 2; ni++)
      ct[(wave * 16 + quad * 4 + r) * 36 + ni * 16 + t16] =
          f32_to_bf16_rne(acc[ni][r]);
  __syncthreads();
  // transpose to B-frag: row=h2, k=d
  {
    int lf = tid & 63, rtl = tid >> 6;
    int rowl = rtl * 16 + (lf & 15);
    int colb = (lf >> 4) << 3;
    __align__(16) u16 o[8];
#pragma unroll
    for (int i = 0; i < 8; i++) o[i] = ct[rowl * 36 + colb + i];
    *(uint4*)(ofrag +
              ((size_t)(((m0 >> 4) + rtl) * 32 + (n0 >> 5)) * 64 + lf) * 8) =
        *(const uint4*)o;
  }
}

// ---------------------------------------------------------------------------
// k_main: out[b][h2] = (x@wct^T-frag GEMM) + sum_p wHI[p]*coh[b][p][h2].
// 512 threads: waves 0-3 = fragment GEMM (m-tile 64 x n-tile 64, 2x2 waves,
// FM=2); waves 4-7 stream this block's coh slice (64x8x64 = 128 KB) into
// LDS. One barrier, merged store. Grid (32,16) = 512 blocks = 2/CU.
// ---------------------------------------------------------------------------
__global__ __launch_bounds__(512, 4) void k_main(
    const u16* __restrict__ Af, const u16* __restrict__ Bf,
    const float* __restrict__ coh, const float* __restrict__ J,
    const float* __restrict__ t, float* __restrict__ out) {
  __shared__ float cs_lds[64 * 68];
  const int tid = threadIdx.x;
  const int wave = tid >> 6, lane = tid & 63;
  const int m0 = blockIdx.x * 64;  // b
  const int n0 = blockIdx.y * 64;  // h2
  const int quad = lane >> 4, t16 = lane & 15;
  const int wm = (wave >> 1) * 32, wn = (wave & 1) * 32;

  f32x4 acc[2][2];
  if (wave < 4) {
    const u16* ap = Af + ((size_t)((m0 + wm) >> 4) * 32) * 512 + lane * 8;
    const u16* bp = Bf + ((size_t)((n0 + wn) >> 4) * 32) * 512 + lane * 8;
#pragma unroll
    for (int mi = 0; mi < 2; mi++)
#pragma unroll
      for (int ni = 0; ni < 2; ni++) acc[mi][ni] = (f32x4){0.f, 0.f, 0.f, 0.f};
#pragma unroll 4
    for (int kt = 0; kt < 32; kt++) {
      bf16x8 a0 = *(const bf16x8*)(ap + kt * 512);
      bf16x8 a1 = *(const bf16x8*)(ap + (32 + kt) * 512);
      bf16x8 b0 = *(const bf16x8*)(bp + kt * 512);
      bf16x8 b1 = *(const bf16x8*)(bp + (32 + kt) * 512);
      acc[0][0] = __builtin_amdgcn_mfma_f32_16x16x32_bf16(a0, b0, acc[0][0], 0, 0, 0);
      acc[0][1] = __builtin_amdgcn_mfma_f32_16x16x32_bf16(a0, b1, acc[0][1], 0, 0, 0);
      acc[1][0] = __builtin_amdgcn_mfma_f32_16x16x32_bf16(a1, b0, acc[1][0], 0, 0, 0);
      acc[1][1] = __builtin_amdgcn_mfma_f32_16x16x32_bf16(a1, b1, acc[1][1], 0, 0, 0);
    }
  } else {
    float wv, alpha;
    wave_scalars(J, t, &wv, &alpha);
    float wHI[8];
#pragma unroll
    for (int p = 0; p < 8; p++) wHI[p] = __shfl(wv, (lane & 56) | p) * alpha;
    const int tc = (wave - 4) * 64 + lane;  // 0..255
    const int c4 = tc & 15;                 // 16B chunk within 64 cols
    const int rb = tc >> 4;                 // base row 0..15
    const float* cb = coh + (size_t)m0 * 8192 + n0 + c4 * 4;
    f32x4 a4[4];
#pragma unroll
    for (int u = 0; u < 4; u++) a4[u] = (f32x4){0.f, 0.f, 0.f, 0.f};
#pragma unroll
    for (int u = 0; u < 4; u++) {
      const float* cr = cb + (size_t)(rb + 16 * u) * 8192;
#pragma unroll
      for (int p = 0; p < 8; p++) a4[u] += wHI[p] * *(const f32x4*)(cr + p * 1024);
    }
#pragma unroll
    for (int u = 0; u < 4; u++)
      *(f32x4*)&cs_lds[(rb + 16 * u) * 68 + c4 * 4] = a4[u];
  }
  __syncthreads();
  if (wave < 4) {
    // C layout: row = quad*4+r, col = t16
#pragma unroll
    for (int mi = 0; mi < 2; mi++)
#pragma unroll
      for (int r = 0; r < 4; r++) {
        const int ml = wm + mi * 16 + quad * 4 + r;
        const size_t mrow = (size_t)(m0 + ml) * 1024;
#pragma unroll
        for (int ni = 0; ni < 2; ni++) {
          const int nl = wn + ni * 16 + t16;
          out[mrow + n0 + nl] = acc[mi][ni][r] + cs_lds[ml * 68 + nl];
        }
      }
  }
}

// ---------------------------------------------------------------------------
extern "C" void kernel_launch(void* const* d_in, const int* in_sizes, int n_in,
                              void* d_out, int out_size, void* d_ws, size_t ws_size,
                              hipStream_t stream) {
  const float* x   = (const float*)d_in[0];  // [2048,1024]
  const float* win = (const float*)d_in[1];  // [1024,1024]
  const float* wp  = (const float*)d_in[2];  // [8,1024,1024]
  const float* J   = (const float*)d_in[3];  // [8,8]
  const float* coh = (const float*)d_in[4];  // [2048,8,1024]
  const float* t   = (const float*)d_in[5];  // [1]
  float* out = (float*)d_out;                // [2048,1024] fp32

  char* ws = (char*)d_ws;
  u16* xfrag   = (u16*)ws;                         // 4 MB, rt=b/16,  kt=d/32
  u16* winfrag = (u16*)(ws + 4u * 1024 * 1024);    // 2 MB, rt=d/16,  kt=h1/32
  u16* wefrag  = (u16*)(ws + 6u * 1024 * 1024);    // 2 MB, rt=h2/16, kt=h1/32
  u16* wctfrag = (u16*)(ws + 8u * 1024 * 1024);    // 2 MB, rt=h2/16, kt=d/32

  k_prep<<<448, 256, 0, stream>>>(x, win, wp, J, t, xfrag, winfrag, wefrag);
  // wct[h2][d] = sum_h1 wefft[h2][h1] * win[d][h1]
  k_gemm0<<<dim3(16, 32), 256, 0, stream>>>(wefrag, winfrag, wctfrag);
  // out[b][h2] = sum_d x[b][d]*wct[h2][d] + sum_p wHI[p]*coh[b][p][h2]
  k_main<<<dim3(32, 16), 512, 0, stream>>>(xfrag, wctfrag, coh, J, t, out);
}

// Round 6
// 158.644 us; speedup vs baseline: 1.0721x; 1.0502x over previous
//
#include <hip/hip_runtime.h>
#include <cstdint>

// ---------------------------------------------------------------------------
// QuantumCoherentLayer collapsed:
//   out[b,h2] = sum_p wHI[p]*coh[b,p,h2] + (x @ Win @ WeffLO)[b,h2]
//   w[j] = (alpha/64)*colsum_j(softmax_rows(cos(phase*J_sym)))
//   wLO = w*(1-alpha) folded into Weff; wHI = w*alpha.
// Frag order: slot = ((rt*32+kt)*64+lane)*8 shorts; lane=(row%16)+16*((k%32)/8)
// holds k%8..+7 (m89-verified; same for A and B operands).
// R6: all stream loads batched into register arrays (force MLP), nontemporal
// on read-once streams, GEMM frag loads batched 4 k-tiles deep.
// ---------------------------------------------------------------------------

typedef __attribute__((ext_vector_type(8))) __bf16 bf16x8;
typedef __attribute__((ext_vector_type(4))) float f32x4;
typedef unsigned short u16;

__device__ __forceinline__ u16 f32_to_bf16_rne(float f) {
  unsigned int u = __float_as_uint(f);
  u += 0x7fffu + ((u >> 16) & 1u);
  return (u16)(u >> 16);
}

__device__ __forceinline__ f32x4 nt_load4(const float* p) {
  return __builtin_nontemporal_load((const f32x4*)p);
}

// Per-wave scalars; lane ends with w for j=(lane&7), plus alpha.
__device__ __forceinline__ void wave_scalars(const float* __restrict__ J,
                                             const float* __restrict__ t,
                                             float* w_out, float* alpha_out) {
  const int lane = threadIdx.x & 63;
  float tv = t[0];
  float alpha = fminf(fmaxf(expf(-tv / 51.0f), 0.0f), 1.0f);
  float phase = 2.0f * 3.14159265358979323846f * 20.0f * tv / 1000.0f;
  int i = lane >> 3, j = lane & 7;
  float jsym = 0.5f * (J[i * 8 + j] + J[j * 8 + i]);
  float e = expf(cosf(phase * jsym));
  float rs = e;
  rs += __shfl_xor(rs, 1);
  rs += __shfl_xor(rs, 2);
  rs += __shfl_xor(rs, 4);
  float p = e / rs;
  float cs = p;
  cs += __shfl_xor(cs, 8);
  cs += __shfl_xor(cs, 16);
  cs += __shfl_xor(cs, 32);
  *w_out = alpha * (1.0f / 64.0f) * cs;
  *alpha_out = alpha;
}

// ---------------------------------------------------------------------------
// k_prep, 704 blocks x 256 (uniform ~64KB reads/block):
//  [0,512)   : wefft 32(h1) x 64(h2) tile: sum_j wLO[j]*Wp[j][h1][h2],
//              LDS transpose -> frag order (rows h2, k h1)
//  [512,640) : x fp32 -> bf16 frag (16 rows/block)
//  [640,704) : Win fp32 -> bf16 frag
// ---------------------------------------------------------------------------
__global__ __launch_bounds__(256, 4) void k_prep(
    const float* __restrict__ x, const float* __restrict__ win,
    const float* __restrict__ wp, const float* __restrict__ J,
    const float* __restrict__ t, u16* __restrict__ xfrag,
    u16* __restrict__ winfrag, u16* __restrict__ wefrag) {
  __shared__ __align__(16) char smem[33024];
  const int blk = blockIdx.x;
  const int tid = threadIdx.x;
  const int lane = tid & 63;

  if (blk < 512) {
    float* lt = (float*)smem;  // [32][68]  lt[h1l][h2l]
    float wv, alpha;
    wave_scalars(J, t, &wv, &alpha);
    float wLO[8];
#pragma unroll
    for (int p = 0; p < 8; p++)
      wLO[p] = __shfl(wv, (lane & 56) | p) * (1.0f - alpha);
    const int a0 = (blk & 31) * 32;  // h1 base
    const int b0 = (blk >> 5) * 64;  // h2 base
    // two items per thread: item = s*256+tid -> row=item>>4 (0..31), chunk=item&15
    f32x4 v[2][8];
#pragma unroll
    for (int s = 0; s < 2; s++) {
      const int item = s * 256 + tid;
      const int row = item >> 4, ch = item & 15;
      const float* base = wp + (size_t)(a0 + row) * 1024 + b0 + ch * 4;
#pragma unroll
      for (int j = 0; j < 8; j++) v[s][j] = nt_load4(base + (size_t)j * 1048576);
    }
#pragma unroll
    for (int s = 0; s < 2; s++) {
      const int item = s * 256 + tid;
      const int row = item >> 4, ch = item & 15;
      f32x4 acc = {0.f, 0.f, 0.f, 0.f};
#pragma unroll
      for (int j = 0; j < 8; j++) acc += wLO[j] * v[s][j];
      *(f32x4*)&lt[row * 68 + ch * 4] = acc;
    }
    __syncthreads();
    // frag write: rt over h2 (4), kt = a0/32; lane lf: row_h2=rtl*16+(lf&15),
    // k_h1 base = (lf>>4)*8
    {
      const int lf = tid & 63, rtl = tid >> 6;
      const int rowh2 = rtl * 16 + (lf & 15);
      const int kh1 = (lf >> 4) << 3;
      __align__(16) u16 o[8];
#pragma unroll
      for (int i = 0; i < 8; i++)
        o[i] = f32_to_bf16_rne(lt[(kh1 + i) * 68 + rowh2]);
      const int rt = (b0 >> 4) + rtl, kt = a0 >> 5;
      *(uint4*)(wefrag + ((size_t)(rt * 32 + kt) * 64 + lf) * 8) = *(const uint4*)o;
    }
  } else {
    const int cid = blk - 512;  // [0,128) x ; [128,192) win
    const float* src;
    u16* dst;
    if (cid < 128) {
      src = x + (size_t)cid * 16384;
      dst = xfrag + (size_t)cid * 16384;
    } else {
      src = win + (size_t)(cid - 128) * 16384;
      dst = winfrag + (size_t)(cid - 128) * 16384;
    }
    u16* ld = (u16*)smem;  // [16][1032]
    f32x4 v[16];
#pragma unroll
    for (int row = 0; row < 16; row++) v[row] = nt_load4(src + row * 1024 + tid * 4);
#pragma unroll
    for (int row = 0; row < 16; row++) {
      ushort4 o;
      o.x = f32_to_bf16_rne(v[row][0]);
      o.y = f32_to_bf16_rne(v[row][1]);
      o.z = f32_to_bf16_rne(v[row][2]);
      o.w = f32_to_bf16_rne(v[row][3]);
      *(ushort4*)(ld + row * 1032 + tid * 4) = o;
    }
    __syncthreads();
#pragma unroll
    for (int s = 0; s < 8; s++) {
      int idx = s * 256 + tid;
      int lf = idx & 63, kt = idx >> 6;
      int row = lf & 15, colb = kt * 32 + ((lf >> 4) << 3);
      *(uint4*)(dst + (kt * 64 + lf) * 8) = *(const uint4*)(ld + row * 1032 + colb);
    }
  }
}

// ---------------------------------------------------------------------------
// k_gemm0: wct frag = wefrag(A, rows h2) x winfrag(B, rows d), K=1024.
// 4 waves stacked in m; m-tile 64, n-tile 32; grid (16,32)=512 blocks.
// Frag loads batched 4 k-tiles deep. Epilogue LDS-transposes C to B-frag.
// ---------------------------------------------------------------------------
__global__ __launch_bounds__(256, 4) void k_gemm0(const u16* __restrict__ Af,
                                                  const u16* __restrict__ Bf,
                                                  u16* __restrict__ ofrag) {
  __shared__ u16 ct[64 * 36];
  const int tid = threadIdx.x;
  const int wave = tid >> 6, lane = tid & 63;
  const int quad = lane >> 4, t16 = lane & 15;
  const int m0 = blockIdx.x * 64;  // h2
  const int n0 = blockIdx.y * 32;  // d
  const u16* ap = Af + ((size_t)((m0 + wave * 16) >> 4) * 32) * 512 + lane * 8;
  const u16* bp = Bf + ((size_t)(n0 >> 4) * 32) * 512 + lane * 8;

  f32x4 acc[2] = {{0.f, 0.f, 0.f, 0.f}, {0.f, 0.f, 0.f, 0.f}};
  for (int kb = 0; kb < 32; kb += 4) {
    bf16x8 a[4], b0[4], b1[4];
#pragma unroll
    for (int u = 0; u < 4; u++) {
      a[u] = *(const bf16x8*)(ap + (kb + u) * 512);
      b0[u] = *(const bf16x8*)(bp + (kb + u) * 512);
      b1[u] = *(const bf16x8*)(bp + (32 + kb + u) * 512);
    }
#pragma unroll
    for (int u = 0; u < 4; u++) {
      acc[0] = __builtin_amdgcn_mfma_f32_16x16x32_bf16(a[u], b0[u], acc[0], 0, 0, 0);
      acc[1] = __builtin_amdgcn_mfma_f32_16x16x32_bf16(a[u], b1[u], acc[1], 0, 0, 0);
    }
  }
#pragma unroll
  for (int r = 0; r < 4; r++)
#pragma unroll
    for (int ni = 0; ni < 2; ni++)
      ct[(wave * 16 + quad * 4 + r) * 36 + ni * 16 + t16] =
          f32_to_bf16_rne(acc[ni][r]);
  __syncthreads();
  {
    int lf = tid & 63, rtl = tid >> 6;
    int rowl = rtl * 16 + (lf & 15);
    int colb = (lf >> 4) << 3;
    __align__(16) u16 o[8];
#pragma unroll
    for (int i = 0; i < 8; i++) o[i] = ct[rowl * 36 + colb + i];
    *(uint4*)(ofrag +
              ((size_t)(((m0 >> 4) + rtl) * 32 + (n0 >> 5)) * 64 + lf) * 8) =
        *(const uint4*)o;
  }
}

// ---------------------------------------------------------------------------
// k_main: out[b][h2] = (x@wct frag GEMM) + sum_p wHI[p]*coh[b][p][h2].
// 512 threads: waves 0-3 fragment GEMM (64x64 tile, 2x2), waves 4-7 stream
// coh (batched 16-deep nontemporal loads) -> LDS. One barrier, merged store.
// Grid (32,16)=512 blocks = 2/CU.
// ---------------------------------------------------------------------------
__global__ __launch_bounds__(512, 4) void k_main(
    const u16* __restrict__ Af, const u16* __restrict__ Bf,
    const float* __restrict__ coh, const float* __restrict__ J,
    const float* __restrict__ t, float* __restrict__ out) {
  __shared__ float cs_lds[64 * 68];
  const int tid = threadIdx.x;
  const int wave = tid >> 6, lane = tid & 63;
  const int m0 = blockIdx.x * 64;  // b
  const int n0 = blockIdx.y * 64;  // h2
  const int quad = lane >> 4, t16 = lane & 15;
  const int wm = (wave >> 1) * 32, wn = (wave & 1) * 32;

  f32x4 acc[2][2];
  if (wave < 4) {
    const u16* ap = Af + ((size_t)((m0 + wm) >> 4) * 32) * 512 + lane * 8;
    const u16* bp = Bf + ((size_t)((n0 + wn) >> 4) * 32) * 512 + lane * 8;
#pragma unroll
    for (int mi = 0; mi < 2; mi++)
#pragma unroll
      for (int ni = 0; ni < 2; ni++) acc[mi][ni] = (f32x4){0.f, 0.f, 0.f, 0.f};
    for (int kb = 0; kb < 32; kb += 4) {
      bf16x8 a0[4], a1[4], b0[4], b1[4];
#pragma unroll
      for (int u = 0; u < 4; u++) {
        a0[u] = *(const bf16x8*)(ap + (kb + u) * 512);
        a1[u] = *(const bf16x8*)(ap + (32 + kb + u) * 512);
        b0[u] = *(const bf16x8*)(bp + (kb + u) * 512);
        b1[u] = *(const bf16x8*)(bp + (32 + kb + u) * 512);
      }
#pragma unroll
      for (int u = 0; u < 4; u++) {
        acc[0][0] = __builtin_amdgcn_mfma_f32_16x16x32_bf16(a0[u], b0[u], acc[0][0], 0, 0, 0);
        acc[0][1] = __builtin_amdgcn_mfma_f32_16x16x32_bf16(a0[u], b1[u], acc[0][1], 0, 0, 0);
        acc[1][0] = __builtin_amdgcn_mfma_f32_16x16x32_bf16(a1[u], b0[u], acc[1][0], 0, 0, 0);
        acc[1][1] = __builtin_amdgcn_mfma_f32_16x16x32_bf16(a1[u], b1[u], acc[1][1], 0, 0, 0);
      }
    }
  } else {
    float wv, alpha;
    wave_scalars(J, t, &wv, &alpha);
    float wHI[8];
#pragma unroll
    for (int p = 0; p < 8; p++) wHI[p] = __shfl(wv, (lane & 56) | p) * alpha;
    const int tc = (wave - 4) * 64 + lane;  // 0..255
    const int c4 = tc & 15;                 // 16B chunk within 64 cols
    const int rb = tc >> 4;                 // base row 0..15
    const float* cb = coh + (size_t)m0 * 8192 + n0 + c4 * 4;
#pragma unroll
    for (int up = 0; up < 2; up++) {  // u-pairs: 16 loads in flight
      f32x4 v[2][8];
#pragma unroll
      for (int h = 0; h < 2; h++) {
        const float* cr = cb + (size_t)(rb + 16 * (up * 2 + h)) * 8192;
#pragma unroll
        for (int p = 0; p < 8; p++) v[h][p] = nt_load4(cr + p * 1024);
      }
#pragma unroll
      for (int h = 0; h < 2; h++) {
        f32x4 a4 = {0.f, 0.f, 0.f, 0.f};
#pragma unroll
        for (int p = 0; p < 8; p++) a4 += wHI[p] * v[h][p];
        *(f32x4*)&cs_lds[(rb + 16 * (up * 2 + h)) * 68 + c4 * 4] = a4;
      }
    }
  }
  __syncthreads();
  if (wave < 4) {
#pragma unroll
    for (int mi = 0; mi < 2; mi++)
#pragma unroll
      for (int r = 0; r < 4; r++) {
        const int ml = wm + mi * 16 + quad * 4 + r;
        const size_t mrow = (size_t)(m0 + ml) * 1024;
#pragma unroll
        for (int ni = 0; ni < 2; ni++) {
          const int nl = wn + ni * 16 + t16;
          out[mrow + n0 + nl] = acc[mi][ni][r] + cs_lds[ml * 68 + nl];
        }
      }
  }
}

// ---------------------------------------------------------------------------
extern "C" void kernel_launch(void* const* d_in, const int* in_sizes, int n_in,
                              void* d_out, int out_size, void* d_ws, size_t ws_size,
                              hipStream_t stream) {
  const float* x   = (const float*)d_in[0];  // [2048,1024]
  const float* win = (const float*)d_in[1];  // [1024,1024]
  const float* wp  = (const float*)d_in[2];  // [8,1024,1024]
  const float* J   = (const float*)d_in[3];  // [8,8]
  const float* coh = (const float*)d_in[4];  // [2048,8,1024]
  const float* t   = (const float*)d_in[5];  // [1]
  float* out = (float*)d_out;                // [2048,1024] fp32

  char* ws = (char*)d_ws;
  u16* xfrag   = (u16*)ws;                         // 4 MB, rt=b/16,  kt=d/32
  u16* winfrag = (u16*)(ws + 4u * 1024 * 1024);    // 2 MB, rt=d/16,  kt=h1/32
  u16* wefrag  = (u16*)(ws + 6u * 1024 * 1024);    // 2 MB, rt=h2/16, kt=h1/32
  u16* wctfrag = (u16*)(ws + 8u * 1024 * 1024);    // 2 MB, rt=h2/16, kt=d/32

  k_prep<<<704, 256, 0, stream>>>(x, win, wp, J, t, xfrag, winfrag, wefrag);
  // wct[h2][d] = sum_h1 wefft[h2][h1] * win[d][h1]
  k_gemm0<<<dim3(16, 32), 256, 0, stream>>>(wefrag, winfrag, wctfrag);
  // out[b][h2] = sum_d x[b][d]*wct[h2][d] + sum_p wHI[p]*coh[b][p][h2]
  k_main<<<dim3(32, 16), 512, 0, stream>>>(xfrag, wctfrag, coh, J, t, out);
}

// Round 7
// 157.107 us; speedup vs baseline: 1.0826x; 1.0098x over previous
//
#include <hip/hip_runtime.h>
#include <cstdint>

// ---------------------------------------------------------------------------
// QuantumCoherentLayer collapsed:
//   out[b,h2] = sum_p wHI[p]*coh[b,p,h2] + (x @ Win @ WeffLO)[b,h2]
//   w[j] = (alpha/64)*colsum_j(softmax_rows(cos(phase*J_sym)))
//   wLO = w*(1-alpha) folded into Weff; wHI = w*alpha.
// Frag order: slot = ((rt*32+kt)*64+lane)*8 shorts; lane=(row%16)+16*((k%32)/8)
// holds k%8..+7 (m89-verified; same for A and B operands).
// R7: launch rebalance (x-convert rides inside the gemm0 launch), XCD-aware
// block swizzle so each XCD's L2 holds its frag working set (<4 MiB).
//   k_prep : wefft frag build (512 blks) + win convert (64 blks)
//   k_mid  : gemm0 wct = weff x win (512 blks, swizzled) + x convert (128)
//   k_main : waves 0-3 frag GEMM, waves 4-7 coh stream -> LDS; swizzled.
// ---------------------------------------------------------------------------

typedef __attribute__((ext_vector_type(8))) __bf16 bf16x8;
typedef __attribute__((ext_vector_type(4))) float f32x4;
typedef unsigned short u16;

__device__ __forceinline__ u16 f32_to_bf16_rne(float f) {
  unsigned int u = __float_as_uint(f);
  u += 0x7fffu + ((u >> 16) & 1u);
  return (u16)(u >> 16);
}

__device__ __forceinline__ f32x4 nt_load4(const float* p) {
  return __builtin_nontemporal_load((const f32x4*)p);
}

// Per-wave scalars; lane ends with w for j=(lane&7), plus alpha.
__device__ __forceinline__ void wave_scalars(const float* __restrict__ J,
                                             const float* __restrict__ t,
                                             float* w_out, float* alpha_out) {
  const int lane = threadIdx.x & 63;
  float tv = t[0];
  float alpha = fminf(fmaxf(expf(-tv / 51.0f), 0.0f), 1.0f);
  float phase = 2.0f * 3.14159265358979323846f * 20.0f * tv / 1000.0f;
  int i = lane >> 3, j = lane & 7;
  float jsym = 0.5f * (J[i * 8 + j] + J[j * 8 + i]);
  float e = expf(cosf(phase * jsym));
  float rs = e;
  rs += __shfl_xor(rs, 1);
  rs += __shfl_xor(rs, 2);
  rs += __shfl_xor(rs, 4);
  float p = e / rs;
  float cs = p;
  cs += __shfl_xor(cs, 8);
  cs += __shfl_xor(cs, 16);
  cs += __shfl_xor(cs, 32);
  *w_out = alpha * (1.0f / 64.0f) * cs;
  *alpha_out = alpha;
}

// fp32 [16 rows x 1024] -> bf16 frag via LDS tile (256 threads)
__device__ __forceinline__ void convert16(const float* __restrict__ src,
                                          u16* __restrict__ dst, u16* ld,
                                          int tid) {
  f32x4 v[16];
#pragma unroll
  for (int row = 0; row < 16; row++) v[row] = nt_load4(src + row * 1024 + tid * 4);
#pragma unroll
  for (int row = 0; row < 16; row++) {
    ushort4 o;
    o.x = f32_to_bf16_rne(v[row][0]);
    o.y = f32_to_bf16_rne(v[row][1]);
    o.z = f32_to_bf16_rne(v[row][2]);
    o.w = f32_to_bf16_rne(v[row][3]);
    *(ushort4*)(ld + row * 1032 + tid * 4) = o;
  }
  __syncthreads();
#pragma unroll
  for (int s = 0; s < 8; s++) {
    int idx = s * 256 + tid;
    int lf = idx & 63, kt = idx >> 6;
    int row = lf & 15, colb = kt * 32 + ((lf >> 4) << 3);
    *(uint4*)(dst + (kt * 64 + lf) * 8) = *(const uint4*)(ld + row * 1032 + colb);
  }
}

// ---------------------------------------------------------------------------
// k_prep, 576 blocks x 256:
//  [0,512)   : wefft 32(h1) x 64(h2) tile -> frag order (rows h2, k h1)
//  [512,576) : Win fp32 -> bf16 frag
// ---------------------------------------------------------------------------
__global__ __launch_bounds__(256, 4) void k_prep(
    const float* __restrict__ win, const float* __restrict__ wp,
    const float* __restrict__ J, const float* __restrict__ t,
    u16* __restrict__ winfrag, u16* __restrict__ wefrag) {
  __shared__ __align__(16) char smem[33024];
  const int blk = blockIdx.x;
  const int tid = threadIdx.x;
  const int lane = tid & 63;

  if (blk < 512) {
    float* lt = (float*)smem;  // [32][68]  lt[h1l][h2l]
    float wv, alpha;
    wave_scalars(J, t, &wv, &alpha);
    float wLO[8];
#pragma unroll
    for (int p = 0; p < 8; p++)
      wLO[p] = __shfl(wv, (lane & 56) | p) * (1.0f - alpha);
    const int a0 = (blk & 31) * 32;  // h1 base
    const int b0 = (blk >> 5) * 64;  // h2 base
    f32x4 v[2][8];
#pragma unroll
    for (int s = 0; s < 2; s++) {
      const int item = s * 256 + tid;
      const int row = item >> 4, ch = item & 15;
      const float* base = wp + (size_t)(a0 + row) * 1024 + b0 + ch * 4;
#pragma unroll
      for (int j = 0; j < 8; j++) v[s][j] = nt_load4(base + (size_t)j * 1048576);
    }
#pragma unroll
    for (int s = 0; s < 2; s++) {
      const int item = s * 256 + tid;
      const int row = item >> 4, ch = item & 15;
      f32x4 acc = {0.f, 0.f, 0.f, 0.f};
#pragma unroll
      for (int j = 0; j < 8; j++) acc += wLO[j] * v[s][j];
      *(f32x4*)&lt[row * 68 + ch * 4] = acc;
    }
    __syncthreads();
    {
      const int lf = tid & 63, rtl = tid >> 6;
      const int rowh2 = rtl * 16 + (lf & 15);
      const int kh1 = (lf >> 4) << 3;
      __align__(16) u16 o[8];
#pragma unroll
      for (int i = 0; i < 8; i++)
        o[i] = f32_to_bf16_rne(lt[(kh1 + i) * 68 + rowh2]);
      const int rt = (b0 >> 4) + rtl, kt = a0 >> 5;
      *(uint4*)(wefrag + ((size_t)(rt * 32 + kt) * 64 + lf) * 8) = *(const uint4*)o;
    }
  } else {
    const int cid = blk - 512;  // 64 blocks
    convert16(win + (size_t)cid * 16384, winfrag + (size_t)cid * 16384,
              (u16*)smem, tid);
  }
}

// ---------------------------------------------------------------------------
// k_mid, 640 blocks x 256:
//  [0,512)   : gemm0  wct frag = wefrag(h2) x winfrag(d), K=1024,
//              tiles 64(h2) x 32(d), XCD-swizzled. Epilogue -> B-frag order.
//  [512,640) : x fp32 -> bf16 frag
// ---------------------------------------------------------------------------
__global__ __launch_bounds__(256, 4) void k_mid(
    const float* __restrict__ x, const u16* __restrict__ Af,
    const u16* __restrict__ Bf, u16* __restrict__ xfrag,
    u16* __restrict__ ofrag) {
  __shared__ __align__(16) char smem[33024];
  const int blk = blockIdx.x;
  const int tid = threadIdx.x;

  if (blk < 512) {
    u16* ct = (u16*)smem;  // [64][36]
    const int wave = tid >> 6, lane = tid & 63;
    const int quad = lane >> 4, t16 = lane & 15;
    // XCD swizzle: per XCD, 2 m-tiles x all 32 n-tiles (A 256KB + B 2MB < 4MB)
    const int xcd = blk & 7, i = blk >> 3;
    const int m0 = (xcd + 8 * (i & 1)) * 64;  // h2
    const int n0 = (i >> 1) * 32;             // d
    const u16* ap = Af + ((size_t)((m0 + wave * 16) >> 4) * 32) * 512 + lane * 8;
    const u16* bp = Bf + ((size_t)(n0 >> 4) * 32) * 512 + lane * 8;

    f32x4 acc[2] = {{0.f, 0.f, 0.f, 0.f}, {0.f, 0.f, 0.f, 0.f}};
    for (int kb = 0; kb < 32; kb += 4) {
      bf16x8 a[4], b0[4], b1[4];
#pragma unroll
      for (int u = 0; u < 4; u++) {
        a[u] = *(const bf16x8*)(ap + (kb + u) * 512);
        b0[u] = *(const bf16x8*)(bp + (kb + u) * 512);
        b1[u] = *(const bf16x8*)(bp + (32 + kb + u) * 512);
      }
#pragma unroll
      for (int u = 0; u < 4; u++) {
        acc[0] = __builtin_amdgcn_mfma_f32_16x16x32_bf16(a[u], b0[u], acc[0], 0, 0, 0);
        acc[1] = __builtin_amdgcn_mfma_f32_16x16x32_bf16(a[u], b1[u], acc[1], 0, 0, 0);
      }
    }
#pragma unroll
    for (int r = 0; r < 4; r++)
#pragma unroll
      for (int ni = 0; ni < 2; ni++)
        ct[(wave * 16 + quad * 4 + r) * 36 + ni * 16 + t16] =
            f32_to_bf16_rne(acc[ni][r]);
    __syncthreads();
    {
      int lf = tid & 63, rtl = tid >> 6;
      int rowl = rtl * 16 + (lf & 15);
      int colb = (lf >> 4) << 3;
      __align__(16) u16 o[8];
#pragma unroll
      for (int i2 = 0; i2 < 8; i2++) o[i2] = ct[rowl * 36 + colb + i2];
      *(uint4*)(ofrag +
                ((size_t)(((m0 >> 4) + rtl) * 32 + (n0 >> 5)) * 64 + lf) * 8) =
          *(const uint4*)o;
    }
  } else {
    const int cid = blk - 512;  // 128 blocks
    convert16(x + (size_t)cid * 16384, xfrag + (size_t)cid * 16384, (u16*)smem,
              tid);
  }
}

// ---------------------------------------------------------------------------
// k_main: out[b][h2] = (x@wct frag GEMM) + sum_p wHI[p]*coh[b][p][h2].
// 512 blocks x 512 thr, XCD-swizzled (per XCD: 4 b-tiles x 16 h2-tiles ->
// A 512KB + B 2MB < 4MB L2). Waves 0-3 GEMM, waves 4-7 stream coh -> LDS.
// ---------------------------------------------------------------------------
__global__ __launch_bounds__(512, 4) void k_main(
    const u16* __restrict__ Af, const u16* __restrict__ Bf,
    const float* __restrict__ coh, const float* __restrict__ J,
    const float* __restrict__ t, float* __restrict__ out) {
  __shared__ float cs_lds[64 * 68];
  const int tid = threadIdx.x;
  const int wave = tid >> 6, lane = tid & 63;
  const int xcd = blockIdx.x & 7, i = blockIdx.x >> 3;
  const int m0 = (xcd + 8 * (i >> 4)) * 64;  // b tile
  const int n0 = (i & 15) * 64;              // h2 tile
  const int quad = lane >> 4, t16 = lane & 15;
  const int wm = (wave >> 1) * 32, wn = (wave & 1) * 32;

  f32x4 acc[2][2];
  if (wave < 4) {
    const u16* ap = Af + ((size_t)((m0 + wm) >> 4) * 32) * 512 + lane * 8;
    const u16* bp = Bf + ((size_t)((n0 + wn) >> 4) * 32) * 512 + lane * 8;
#pragma unroll
    for (int mi = 0; mi < 2; mi++)
#pragma unroll
      for (int ni = 0; ni < 2; ni++) acc[mi][ni] = (f32x4){0.f, 0.f, 0.f, 0.f};
    for (int kb = 0; kb < 32; kb += 4) {
      bf16x8 a0[4], a1[4], b0[4], b1[4];
#pragma unroll
      for (int u = 0; u < 4; u++) {
        a0[u] = *(const bf16x8*)(ap + (kb + u) * 512);
        a1[u] = *(const bf16x8*)(ap + (32 + kb + u) * 512);
        b0[u] = *(const bf16x8*)(bp + (kb + u) * 512);
        b1[u] = *(const bf16x8*)(bp + (32 + kb + u) * 512);
      }
#pragma unroll
      for (int u = 0; u < 4; u++) {
        acc[0][0] = __builtin_amdgcn_mfma_f32_16x16x32_bf16(a0[u], b0[u], acc[0][0], 0, 0, 0);
        acc[0][1] = __builtin_amdgcn_mfma_f32_16x16x32_bf16(a0[u], b1[u], acc[0][1], 0, 0, 0);
        acc[1][0] = __builtin_amdgcn_mfma_f32_16x16x32_bf16(a1[u], b0[u], acc[1][0], 0, 0, 0);
        acc[1][1] = __builtin_amdgcn_mfma_f32_16x16x32_bf16(a1[u], b1[u], acc[1][1], 0, 0, 0);
      }
    }
  } else {
    float wv, alpha;
    wave_scalars(J, t, &wv, &alpha);
    float wHI[8];
#pragma unroll
    for (int p = 0; p < 8; p++) wHI[p] = __shfl(wv, (lane & 56) | p) * alpha;
    const int tc = (wave - 4) * 64 + lane;  // 0..255
    const int c4 = tc & 15;                 // 16B chunk within 64 cols
    const int rb = tc >> 4;                 // base row 0..15
    const float* cb = coh + (size_t)m0 * 8192 + n0 + c4 * 4;
#pragma unroll
    for (int up = 0; up < 2; up++) {  // 16 loads in flight per burst
      f32x4 v[2][8];
#pragma unroll
      for (int h = 0; h < 2; h++) {
        const float* cr = cb + (size_t)(rb + 16 * (up * 2 + h)) * 8192;
#pragma unroll
        for (int p = 0; p < 8; p++) v[h][p] = nt_load4(cr + p * 1024);
      }
#pragma unroll
      for (int h = 0; h < 2; h++) {
        f32x4 a4 = {0.f, 0.f, 0.f, 0.f};
#pragma unroll
        for (int p = 0; p < 8; p++) a4 += wHI[p] * v[h][p];
        *(f32x4*)&cs_lds[(rb + 16 * (up * 2 + h)) * 68 + c4 * 4] = a4;
      }
    }
  }
  __syncthreads();
  if (wave < 4) {
#pragma unroll
    for (int mi = 0; mi < 2; mi++)
#pragma unroll
      for (int r = 0; r < 4; r++) {
        const int ml = wm + mi * 16 + quad * 4 + r;
        const size_t mrow = (size_t)(m0 + ml) * 1024;
#pragma unroll
        for (int ni = 0; ni < 2; ni++) {
          const int nl = wn + ni * 16 + t16;
          out[mrow + n0 + nl] = acc[mi][ni][r] + cs_lds[ml * 68 + nl];
        }
      }
  }
}

// ---------------------------------------------------------------------------
extern "C" void kernel_launch(void* const* d_in, const int* in_sizes, int n_in,
                              void* d_out, int out_size, void* d_ws, size_t ws_size,
                              hipStream_t stream) {
  const float* x   = (const float*)d_in[0];  // [2048,1024]
  const float* win = (const float*)d_in[1];  // [1024,1024]
  const float* wp  = (const float*)d_in[2];  // [8,1024,1024]
  const float* J   = (const float*)d_in[3];  // [8,8]
  const float* coh = (const float*)d_in[4];  // [2048,8,1024]
  const float* t   = (const float*)d_in[5];  // [1]
  float* out = (float*)d_out;                // [2048,1024] fp32

  char* ws = (char*)d_ws;
  u16* xfrag   = (u16*)ws;                         // 4 MB, rt=b/16,  kt=d/32
  u16* winfrag = (u16*)(ws + 4u * 1024 * 1024);    // 2 MB, rt=d/16,  kt=h1/32
  u16* wefrag  = (u16*)(ws + 6u * 1024 * 1024);    // 2 MB, rt=h2/16, kt=h1/32
  u16* wctfrag = (u16*)(ws + 8u * 1024 * 1024);    // 2 MB, rt=h2/16, kt=d/32

  // wefft build + win convert
  k_prep<<<576, 256, 0, stream>>>(win, wp, J, t, winfrag, wefrag);
  // wct[h2][d] = sum_h1 weff[h2][h1]*win[d][h1]  (+ x convert riding along)
  k_mid<<<640, 256, 0, stream>>>(x, wefrag, winfrag, xfrag, wctfrag);
  // out[b][h2] = sum_d x[b][d]*wct[h2][d] + sum_p wHI[p]*coh[b][p][h2]
  k_main<<<512, 512, 0, stream>>>(xfrag, wctfrag, coh, J, t, out);
}